// Round 3
// baseline (3475.396 us; speedup 1.0000x reference)
//
#include <hip/hip_runtime.h>
#include <hip/hip_bf16.h>
#include <math.h>
#include <stdint.h>

#define BATCH 8
#define NTOK  4096
#define DIM   256
#define SK    256
#define CAND  32      // max candidates stored per (query, half)

typedef __attribute__((ext_vector_type(8))) short short8;   // 8 bf16
typedef __attribute__((ext_vector_type(4))) float float4v;  // 4 f32 acc
typedef unsigned short ushort_t;

#define GLOAD_LDS16(gp, lp)                                                    \
  __builtin_amdgcn_global_load_lds(                                            \
      (const __attribute__((address_space(1))) unsigned int*)(gp),             \
      (__attribute__((address_space(3))) unsigned int*)(lp), 16, 0, 0)

// ---------------- threefry2x32 (JAX partitionable counter mode) ----------------
__device__ __forceinline__ uint32_t rotl32(uint32_t v, uint32_t r) {
  return (v << r) | (v >> (32u - r));
}
__device__ __forceinline__ void tf_round4(uint32_t& x0, uint32_t& x1,
                                          uint32_t r0, uint32_t r1,
                                          uint32_t r2, uint32_t r3) {
  x0 += x1; x1 = rotl32(x1, r0); x1 ^= x0;
  x0 += x1; x1 = rotl32(x1, r1); x1 ^= x0;
  x0 += x1; x1 = rotl32(x1, r2); x1 ^= x0;
  x0 += x1; x1 = rotl32(x1, r3); x1 ^= x0;
}
__device__ __forceinline__ uint32_t threefry_bits32(uint32_t c_hi, uint32_t c_lo) {
  const uint32_t k0 = 0u, k1 = 42u;
  const uint32_t k2 = k0 ^ k1 ^ 0x1BD11BDAu;
  uint32_t x0 = c_hi + k0;
  uint32_t x1 = c_lo + k1;
  tf_round4(x0, x1, 13u, 15u, 26u, 6u);  x0 += k1; x1 += k2 + 1u;
  tf_round4(x0, x1, 17u, 29u, 16u, 24u); x0 += k2; x1 += k0 + 2u;
  tf_round4(x0, x1, 13u, 15u, 26u, 6u);  x0 += k0; x1 += k1 + 3u;
  tf_round4(x0, x1, 17u, 29u, 16u, 24u); x0 += k1; x1 += k2 + 4u;
  tf_round4(x0, x1, 13u, 15u, 26u, 6u);  x0 += k2; x1 += k0 + 5u;
  return x0 ^ x1;
}

// ---------------- kernel 0: init per-batch max-norm accumulators ----------------
__global__ void init_kernel(unsigned int* __restrict__ maxn2u) {
  if (threadIdx.x < BATCH) maxn2u[threadIdx.x] = 0u;
}

// ---------------- kernel 1: bf16 cast + row squared norms + batch max ----------
__global__ __launch_bounds__(256) void split_rowsq_kernel(
    const float* __restrict__ x, ushort_t* __restrict__ xh,
    float* __restrict__ sqf, unsigned int* __restrict__ maxn2u) {
  const int row  = blockIdx.x * 4 + (threadIdx.x >> 6);   // [0, BATCH*NTOK)
  const int lane = threadIdx.x & 63;
  const float4 v4 = ((const float4*)(x + (size_t)row * DIM))[lane];
  ushort_t h[4];
  float acc = 0.0f;
  const float vv[4] = {v4.x, v4.y, v4.z, v4.w};
#pragma unroll
  for (int i = 0; i < 4; ++i) {
    __hip_bfloat16 b = __float2bfloat16(vv[i]);           // RNE
    h[i] = *(ushort_t*)&b;
    acc += vv[i] * vv[i];
  }
  *(ushort_t*)&((short8*)0)[0];  // (no-op; keeps types honest)
  ((ushort_t*)xh)[0] = ((ushort_t*)xh)[0];                // avoid unused warnings path
  // store 4 bf16 contiguous
  *(uint64_t*)(xh + (size_t)row * DIM + lane * 4) =
      (uint64_t)h[0] | ((uint64_t)h[1] << 16) | ((uint64_t)h[2] << 32) | ((uint64_t)h[3] << 48);
#pragma unroll
  for (int off = 32; off > 0; off >>= 1) acc += __shfl_down(acc, off, 64);
  if (lane == 0) {
    sqf[row] = acc;
    atomicMax(&maxn2u[row >> 12], __float_as_uint(acc));  // acc >= 0: uint order ok
  }
}

// ---------------- kernel 2: 1-pass MFMA GEMM + per-query candidate selection ----
// block: 128 q-rows x 2048 m-half; 4 waves in 2x2, each 64x64 output per m-tile
__global__ __launch_bounds__(256, 2) void gemm_knn_kernel(
    const ushort_t* __restrict__ xh, const float* __restrict__ sqf,
    const unsigned int* __restrict__ maxn2u, int* __restrict__ cand) {
  __shared__ ushort_t Ah[128 * 256];                      // 64 KB, swizzled
  __shared__ union {
    ushort_t Bt[128 * 64];                                // 16 KB, swizzled
    float    Ct[64 * 64];                                 // 16 KB, q-swizzled (transposed)
    struct { float mv[64][4][10]; ushort_t mi[64][4][10]; } M;  // 15 KB
  } U;

  const int blk = blockIdx.x;
  const int b   = blk >> 6;                               // 64 blocks per batch
  const int qt  = (blk >> 1) & 31;
  const int hf  = blk & 1;
  const int q0  = qt * 128;
  const int mbase = hf * 2048;

  const int t = threadIdx.x;
  const int w = t >> 6;
  const int l = t & 63;

  const ushort_t* xhb = xh + (size_t)b * NTOK * DIM;
  const float* sqb = sqf + b * NTOK;

  // ---- stage persistent swizzled A panel: 128 rows x 256 cols bf16 ----
#pragma unroll
  for (int is = 0; is < 16; ++is) {
    const int row = is * 8 + (t >> 5);
    const int cg  = (t & 31) ^ (row & 7);
    GLOAD_LDS16(xhb + (size_t)(q0 + row) * DIM + cg * 8,
                (char*)Ah + is * 4096 + t * 16);
  }

  const int q6 = t & 63;
  const float sqq0 = sqb[q0 + q6];
  const float sqq1 = sqb[q0 + 64 + q6];

  float tv0[10], tv1[10];
  int   ti0[10], ti1[10];
#pragma unroll
  for (int j = 0; j < 10; ++j) { tv0[j] = 3.0e38f; tv1[j] = 3.0e38f; ti0[j] = 0; ti1[j] = 0; }

  for (int mt = 0; mt < 16; ++mt) {
    const int m0 = mbase + mt * 128;                      // within-batch token base
    float4v acc[4][4];
#pragma unroll
    for (int i = 0; i < 4; ++i)
#pragma unroll
      for (int j = 0; j < 4; ++j) acc[i][j] = (float4v){0.f, 0.f, 0.f, 0.f};

    for (int ki = 0; ki < 4; ++ki) {
      const int kb = ki * 64;
      __syncthreads();                                    // prior use of U done
#pragma unroll
      for (int is = 0; is < 4; ++is) {
        const int row = is * 32 + (t >> 3);
        const int cg  = (t & 7) ^ (row & 7);
        GLOAD_LDS16(xhb + (size_t)(m0 + row) * DIM + kb + cg * 8,
                    (char*)U.Bt + is * 4096 + t * 16);
      }
      __syncthreads();                                    // loads landed

      short8 af[2][4], bf[2][4];
#pragma unroll
      for (int kk = 0; kk < 2; ++kk)
#pragma unroll
        for (int i = 0; i < 4; ++i) {
          const int row = (w >> 1) * 64 + i * 16 + (l & 15);
          const int cgx = ((kb >> 3) + kk * 4 + (l >> 4)) ^ (l & 7);
          af[kk][i] = *(const short8*)(Ah + row * 256 + cgx * 8);
        }
#pragma unroll
      for (int kk = 0; kk < 2; ++kk)
#pragma unroll
        for (int j = 0; j < 4; ++j) {
          const int row = (w & 1) * 64 + j * 16 + (l & 15);
          const int cgx = (kk * 4 + (l >> 4)) ^ (l & 7);
          bf[kk][j] = *(const short8*)(U.Bt + row * 64 + cgx * 8);
        }
#pragma unroll
      for (int kk = 0; kk < 2; ++kk)
#pragma unroll
        for (int i = 0; i < 4; ++i)
#pragma unroll
          for (int j = 0; j < 4; ++j)
            acc[i][j] = __builtin_amdgcn_mfma_f32_16x16x32_bf16(af[kk][i], bf[kk][j], acc[i][j], 0, 0, 0);
    }

    // ---- epilogue: 4 phases, one wave's 64x64 acc each, transposed C roundtrip ----
#pragma unroll
    for (int ph = 0; ph < 4; ++ph) {
      __syncthreads();
      if (w == ph) {
#pragma unroll
        for (int i = 0; i < 4; ++i)
#pragma unroll
          for (int j = 0; j < 4; ++j) {
            const int c    = j * 16 + (l & 15);           // m-local (0..63)
            const int qg4  = i * 4 + (l >> 4);            // q-group (q = qg4*4+r)
            const int qg4x = qg4 ^ (l & 15);              // swizzle: (q>>2)^(c&15)
            *(float4v*)&U.Ct[c * 64 + qg4x * 4] = acc[i][j];
          }
      }
      __syncthreads();
      const int rh = ph >> 1, ch = ph & 1;
      const int qb  = q0 + rh * 64 + q6;                  // within-batch q
      const float sqq = rh ? sqq1 : sqq0;
      const int s = t >> 6;
#pragma unroll
      for (int e = 0; e < 16; ++e) {
        const int c  = s * 16 + e;
        const int mg = m0 + ch * 64 + c;                  // within-batch m
        const int qx = ((q6 >> 2) ^ (c & 15)) * 4 + (q6 & 3);
        const float dot = U.Ct[c * 64 + qx];
        const float d2a = sqq + sqb[mg] - 2.0f * dot;
        if (rh == 0) {
          if (mg != qb && d2a < tv0[9]) {
            tv0[9] = d2a; ti0[9] = mg;
#pragma unroll
            for (int k2 = 9; k2 > 0; --k2)
              if (tv0[k2] < tv0[k2 - 1]) {
                float tf2 = tv0[k2]; tv0[k2] = tv0[k2 - 1]; tv0[k2 - 1] = tf2;
                int tix = ti0[k2]; ti0[k2] = ti0[k2 - 1]; ti0[k2 - 1] = tix;
              }
          }
        } else {
          if (mg != qb && d2a < tv1[9]) {
            tv1[9] = d2a; ti1[9] = mg;
#pragma unroll
            for (int k2 = 9; k2 > 0; --k2)
              if (tv1[k2] < tv1[k2 - 1]) {
                float tf2 = tv1[k2]; tv1[k2] = tv1[k2 - 1]; tv1[k2 - 1] = tf2;
                int tix = ti1[k2]; ti1[k2] = ti1[k2 - 1]; ti1[k2 - 1] = tix;
              }
          }
        }
      }
    }
  }

  // ---- merge per rh-half: 4 slices x top-10 -> threshold -> candidate list ----
  const float mn2 = __uint_as_float(maxn2u[b]);
#pragma unroll
  for (int rh = 0; rh < 2; ++rh) {
    __syncthreads();
#pragma unroll
    for (int j = 0; j < 10; ++j) {
      U.M.mv[q6][t >> 6][j] = rh ? tv1[j] : tv0[j];
      U.M.mi[q6][t >> 6][j] = (ushort_t)(rh ? ti1[j] : ti0[j]);
    }
    __syncthreads();
    if (t < 64) {
      const int q = q0 + rh * 64 + t;
      float t5[5] = {3.0e38f, 3.0e38f, 3.0e38f, 3.0e38f, 3.0e38f};
      for (int s = 0; s < 4; ++s)
#pragma unroll
        for (int j = 0; j < 10; ++j) {
          const float v = U.M.mv[t][s][j];
          if (v < t5[4]) {
            t5[4] = v;
#pragma unroll
            for (int k2 = 4; k2 > 0; --k2)
              if (t5[k2] < t5[k2 - 1]) { float tf2 = t5[k2]; t5[k2] = t5[k2 - 1]; t5[k2 - 1] = tf2; }
          }
        }
      // sound margin: 2*eps_d2, eps_dot <= 2^-9*2.02*|q||m|  (bf16 RNE + f32 acc)
      const float T = t5[4] + 0.016f * sqrtf(sqb[q] * mn2) + 0.01f;
      int cnt = 0, ov = 0;
      int* cq = cand + ((size_t)(b * NTOK + q) * 2 + hf) * (CAND + 1);
      for (int s = 0; s < 4; ++s) {
        if (U.M.mv[t][s][9] <= T) ov = 1;                 // slice may hide candidates
#pragma unroll
        for (int j = 0; j < 10; ++j) {
          const float v = U.M.mv[t][s][j];
          if (v <= T) {
            if (cnt < CAND) cq[1 + cnt] = (int)U.M.mi[t][s][j];
            ++cnt;
          }
        }
      }
      if (cnt > CAND) ov = 1;
      cq[0] = ov ? -1 : cnt;
    }
  }
}

// ---------------- kernel 3: exact f64 kNN distance on candidates ----------------
__global__ __launch_bounds__(256) void exact_knn_kernel(
    const float* __restrict__ x, const int* __restrict__ cand,
    double* __restrict__ dk2) {
  const int qg = blockIdx.x * 4 + (threadIdx.x >> 6);     // [0, BATCH*NTOK)
  const int l  = threadIdx.x & 63;
  const int b  = qg >> 12;
  const int q  = qg & (NTOK - 1);
  const float* xb = x + (size_t)b * NTOK * DIM;
  const int* c0 = cand + ((size_t)qg * 2 + 0) * (CAND + 1);
  const int* c1 = cand + ((size_t)qg * 2 + 1) * (CAND + 1);
  const int n0 = c0[0], n1 = c1[0];

  double xq[4];
#pragma unroll
  for (int i = 0; i < 4; ++i) xq[i] = (double)xb[(size_t)q * DIM + l + i * 64];

  double t5[5] = {1e300, 1e300, 1e300, 1e300, 1e300};
  const bool full = (n0 < 0) || (n1 < 0);
  const int n_iter = full ? NTOK : (n0 + n1);
  for (int c = 0; c < n_iter; ++c) {
    int m;
    if (full) { m = c; if (m == q) continue; }
    else m = (c < n0) ? c0[1 + c] : c1[1 + (c - n0)];
    double acc = 0.0;
#pragma unroll
    for (int i = 0; i < 4; ++i) {
      const double d = xq[i] - (double)xb[(size_t)m * DIM + l + i * 64];
      acc += d * d;
    }
#pragma unroll
    for (int off = 32; off > 0; off >>= 1) acc += __shfl_xor(acc, off, 64);
    if (acc < t5[4]) {
      t5[4] = acc;
#pragma unroll
      for (int k2 = 4; k2 > 0; --k2)
        if (t5[k2] < t5[k2 - 1]) { double tmp = t5[k2]; t5[k2] = t5[k2 - 1]; t5[k2 - 1] = tmp; }
    }
  }
  if (l == 0) dk2[qg] = t5[4];
}

// ---------------- kernel 4: gumbel + score (f64) ----------------
__global__ __launch_bounds__(256) void score_kernel(const double* __restrict__ dk2,
                                                    double* __restrict__ scores) {
  const int i = blockIdx.x * 256 + threadIdx.x;
  const uint32_t bits = threefry_bits32(0u, (uint32_t)i);
  const uint32_t fb = (bits >> 9) | 0x3F800000u;
  float uf = __uint_as_float(fb) - 1.0f;
  const float tiny = 1.17549435082228750797e-38f;
  uf += tiny;
  if (uf < tiny) uf = tiny;
  const double g = -log(-log((double)uf));
  const double w = sqrt(dk2[i] + 1e-12);
  scores[i] = log(w + 1e-12) + g;
}

// ---------------- kernel 5: stable rank-select top-256 (no barriers in hot loop) -
__global__ __launch_bounds__(256) void rank_topk_kernel(
    const double* __restrict__ scores, int* __restrict__ sel) {
  __shared__ double K[NTOK];                              // 32 KB
  const int b   = blockIdx.x >> 4;
  const int seg = blockIdx.x & 15;
  const int t   = threadIdx.x;
  for (int i = t; i < NTOK; i += 256) K[i] = scores[(size_t)b * NTOK + i];
  __syncthreads();
  const int i = seg * 256 + t;
  const double ki = K[i];
  int r = 0;
  for (int j = 0; j < NTOK; j += 4) {
#pragma unroll
    for (int u = 0; u < 4; ++u) {
      const double kj = K[j + u];
      r += (kj > ki || (kj == ki && (j + u) < i)) ? 1 : 0;
    }
  }
  if (r < SK) sel[b * SK + r] = i;
}

// ---------------- kernel 6: gather sampled rows ----------------
__global__ __launch_bounds__(256) void gather_kernel(const float* __restrict__ x,
                                                     const int* __restrict__ sel,
                                                     float* __restrict__ out) {
  const int blk = blockIdx.x;                             // BATCH*SK blocks
  const int b = blk >> 8;
  const int r = blk & 255;
  const int t = threadIdx.x;
  const int src = sel[b * SK + r];
  out[((size_t)(b * SK + r)) * DIM + t] = x[((size_t)(b * NTOK + src)) * DIM + t];
  if (blk == 0 && t == 0) out[(size_t)BATCH * SK * DIM] = 0.0f;  // 2nd output: 0.0
}

extern "C" void kernel_launch(void* const* d_in, const int* in_sizes, int n_in,
                              void* d_out, int out_size, void* d_ws, size_t ws_size,
                              hipStream_t stream) {
  const float* x = (const float*)d_in[0];
  float* out = (float*)d_out;
  char* ws = (char*)d_ws;

  ushort_t* xh        = (ushort_t*)(ws + 0);              // 16 MB
  float*    sqf       = (float*)(ws + 16777216);          // 128 KB
  unsigned int* maxn2 = (unsigned int*)(ws + 16908288);   // 256 B
  double*   dk2       = (double*)(ws + 16908544);         // 256 KB
  double*   scores    = (double*)(ws + 17170688);         // 256 KB
  int*      sel       = (int*)(ws + 17432832);            // 8 KB
  int*      cand      = (int*)(ws + 17441024);            // ~8.7 MB

  init_kernel<<<1, 64, 0, stream>>>(maxn2);
  split_rowsq_kernel<<<BATCH * NTOK / 4, 256, 0, stream>>>(x, xh, sqf, maxn2);
  gemm_knn_kernel<<<BATCH * 64, 256, 0, stream>>>(xh, sqf, maxn2, cand);
  exact_knn_kernel<<<BATCH * NTOK / 4, 256, 0, stream>>>(x, cand, dk2);
  score_kernel<<<BATCH * NTOK / 256, 256, 0, stream>>>(dk2, scores);
  rank_topk_kernel<<<BATCH * 16, 256, 0, stream>>>(scores, sel);
  gather_kernel<<<BATCH * SK, 256, 0, stream>>>(x, sel, out);
}

// Round 4
// 1325.205 us; speedup vs baseline: 2.6225x; 2.6225x over previous
//
#include <hip/hip_runtime.h>
#include <hip/hip_bf16.h>
#include <math.h>
#include <stdint.h>

#define BATCH 8
#define NTOK  4096
#define DIM   256
#define SK    256
#define CAND  32      // max candidates stored per (query, half)
#define OVCAP 65536   // fallback list capacity (covers worst case)

typedef __attribute__((ext_vector_type(8))) short short8;   // 8 bf16
typedef __attribute__((ext_vector_type(4))) float float4v;  // 4 f32 acc
typedef unsigned short ushort_t;

#define GLOAD_LDS16(gp, lp)                                                    \
  __builtin_amdgcn_global_load_lds(                                            \
      (const __attribute__((address_space(1))) unsigned int*)(gp),             \
      (__attribute__((address_space(3))) unsigned int*)(lp), 16, 0, 0)

// ---------------- threefry2x32 (JAX partitionable counter mode) ----------------
__device__ __forceinline__ uint32_t rotl32(uint32_t v, uint32_t r) {
  return (v << r) | (v >> (32u - r));
}
__device__ __forceinline__ void tf_round4(uint32_t& x0, uint32_t& x1,
                                          uint32_t r0, uint32_t r1,
                                          uint32_t r2, uint32_t r3) {
  x0 += x1; x1 = rotl32(x1, r0); x1 ^= x0;
  x0 += x1; x1 = rotl32(x1, r1); x1 ^= x0;
  x0 += x1; x1 = rotl32(x1, r2); x1 ^= x0;
  x0 += x1; x1 = rotl32(x1, r3); x1 ^= x0;
}
__device__ __forceinline__ uint32_t threefry_bits32(uint32_t c_hi, uint32_t c_lo) {
  const uint32_t k0 = 0u, k1 = 42u;
  const uint32_t k2 = k0 ^ k1 ^ 0x1BD11BDAu;
  uint32_t x0 = c_hi + k0;
  uint32_t x1 = c_lo + k1;
  tf_round4(x0, x1, 13u, 15u, 26u, 6u);  x0 += k1; x1 += k2 + 1u;
  tf_round4(x0, x1, 17u, 29u, 16u, 24u); x0 += k2; x1 += k0 + 2u;
  tf_round4(x0, x1, 13u, 15u, 26u, 6u);  x0 += k0; x1 += k1 + 3u;
  tf_round4(x0, x1, 17u, 29u, 16u, 24u); x0 += k1; x1 += k2 + 4u;
  tf_round4(x0, x1, 13u, 15u, 26u, 6u);  x0 += k2; x1 += k0 + 5u;
  return x0 ^ x1;
}

// ---------------- kernel 0: zero counters (ws is poisoned every launch) --------
__global__ void init_kernel(unsigned int* __restrict__ maxn2u,
                            unsigned int* __restrict__ ovcnt) {
  if (threadIdx.x < BATCH) maxn2u[threadIdx.x] = 0u;
  if (threadIdx.x == 63) *ovcnt = 0u;
}

// ---------------- kernel 1: bf16 cast + row squared norms + batch max-norm ------
__global__ __launch_bounds__(256) void split_rowsq_kernel(
    const float* __restrict__ x, ushort_t* __restrict__ xh,
    float* __restrict__ sqf, unsigned int* __restrict__ maxn2u) {
  const int row  = blockIdx.x * 4 + (threadIdx.x >> 6);   // [0, BATCH*NTOK)
  const int lane = threadIdx.x & 63;
  const float4 v4 = ((const float4*)(x + (size_t)row * DIM))[lane];
  const float vv[4] = {v4.x, v4.y, v4.z, v4.w};
  ushort_t h[4];
  float acc = 0.0f;
#pragma unroll
  for (int i = 0; i < 4; ++i) {
    __hip_bfloat16 b = __float2bfloat16(vv[i]);           // RNE
    h[i] = *(ushort_t*)&b;
    acc += vv[i] * vv[i];
  }
  *(uint64_t*)(xh + (size_t)row * DIM + lane * 4) =
      (uint64_t)h[0] | ((uint64_t)h[1] << 16) | ((uint64_t)h[2] << 32) | ((uint64_t)h[3] << 48);
#pragma unroll
  for (int off = 32; off > 0; off >>= 1) acc += __shfl_down(acc, off, 64);
  if (lane == 0) {
    sqf[row] = acc;
    atomicMax(&maxn2u[row >> 12], __float_as_uint(acc));  // acc >= 0: uint order ok
  }
}

// ---------------- kernel 2: 1-pass MFMA GEMM + per-query candidate selection ----
__global__ __launch_bounds__(256, 2) void gemm_knn_kernel(
    const ushort_t* __restrict__ xh, const float* __restrict__ sqf,
    const unsigned int* __restrict__ maxn2u, int* __restrict__ cand,
    unsigned int* __restrict__ ovcnt, int* __restrict__ ovlist) {
  __shared__ ushort_t Ah[128 * 256];                      // 64 KB, swizzled
  __shared__ union {
    ushort_t Bt[128 * 64];                                // 16 KB, swizzled
    float    Ct[64 * 64];                                 // 16 KB, q-swizzled (transposed)
    struct { float mv[64][4][10]; ushort_t mi[64][4][10]; } M;  // 15 KB
  } U;

  const int blk = blockIdx.x;
  const int b   = blk >> 6;                               // 64 blocks per batch
  const int qt  = (blk >> 1) & 31;
  const int hf  = blk & 1;
  const int q0  = qt * 128;
  const int mbase = hf * 2048;

  const int t = threadIdx.x;
  const int w = t >> 6;
  const int l = t & 63;

  const ushort_t* xhb = xh + (size_t)b * NTOK * DIM;
  const float* sqb = sqf + b * NTOK;

  // ---- stage persistent swizzled A panel: 128 rows x 256 cols bf16 ----
#pragma unroll
  for (int is = 0; is < 16; ++is) {
    const int row = is * 8 + (t >> 5);
    const int cg  = (t & 31) ^ (row & 7);
    GLOAD_LDS16(xhb + (size_t)(q0 + row) * DIM + cg * 8,
                (char*)Ah + is * 4096 + t * 16);
  }

  const int q6 = t & 63;
  const float sqq0 = sqb[q0 + q6];
  const float sqq1 = sqb[q0 + 64 + q6];

  float tv0[10], tv1[10];
  int   ti0[10], ti1[10];
#pragma unroll
  for (int j = 0; j < 10; ++j) { tv0[j] = 3.0e38f; tv1[j] = 3.0e38f; ti0[j] = 0; ti1[j] = 0; }

  for (int mt = 0; mt < 16; ++mt) {
    const int m0 = mbase + mt * 128;                      // within-batch token base
    float4v acc[4][4];
#pragma unroll
    for (int i = 0; i < 4; ++i)
#pragma unroll
      for (int j = 0; j < 4; ++j) acc[i][j] = (float4v){0.f, 0.f, 0.f, 0.f};

    for (int ki = 0; ki < 4; ++ki) {
      const int kb = ki * 64;
      __syncthreads();                                    // prior use of U done
#pragma unroll
      for (int is = 0; is < 4; ++is) {
        const int row = is * 32 + (t >> 3);
        const int cg  = (t & 7) ^ (row & 7);
        GLOAD_LDS16(xhb + (size_t)(m0 + row) * DIM + kb + cg * 8,
                    (char*)U.Bt + is * 4096 + t * 16);
      }
      __syncthreads();                                    // loads landed

      short8 af[2][4], bf[2][4];
#pragma unroll
      for (int kk = 0; kk < 2; ++kk)
#pragma unroll
        for (int i = 0; i < 4; ++i) {
          const int row = (w >> 1) * 64 + i * 16 + (l & 15);
          const int cgx = ((kb >> 3) + kk * 4 + (l >> 4)) ^ (l & 7);
          af[kk][i] = *(const short8*)(Ah + row * 256 + cgx * 8);
        }
#pragma unroll
      for (int kk = 0; kk < 2; ++kk)
#pragma unroll
        for (int j = 0; j < 4; ++j) {
          const int row = (w & 1) * 64 + j * 16 + (l & 15);
          const int cgx = (kk * 4 + (l >> 4)) ^ (l & 7);
          bf[kk][j] = *(const short8*)(U.Bt + row * 64 + cgx * 8);
        }
#pragma unroll
      for (int kk = 0; kk < 2; ++kk)
#pragma unroll
        for (int i = 0; i < 4; ++i)
#pragma unroll
          for (int j = 0; j < 4; ++j)
            acc[i][j] = __builtin_amdgcn_mfma_f32_16x16x32_bf16(af[kk][i], bf[kk][j], acc[i][j], 0, 0, 0);
    }

    // ---- epilogue: 4 phases, one wave's 64x64 acc each, transposed C roundtrip ----
#pragma unroll
    for (int ph = 0; ph < 4; ++ph) {
      __syncthreads();
      if (w == ph) {
#pragma unroll
        for (int i = 0; i < 4; ++i)
#pragma unroll
          for (int j = 0; j < 4; ++j) {
            const int c    = j * 16 + (l & 15);           // m-local (0..63)
            const int qg4  = i * 4 + (l >> 4);            // q-group (q = qg4*4+r)
            const int qg4x = qg4 ^ (l & 15);              // swizzle with c&15
            *(float4v*)&U.Ct[c * 64 + qg4x * 4] = acc[i][j];
          }
      }
      __syncthreads();
      const int rh = ph >> 1, ch = ph & 1;
      const int qb  = q0 + rh * 64 + q6;                  // within-batch q
      const float sqq = rh ? sqq1 : sqq0;
      const int s = t >> 6;
#pragma unroll
      for (int e = 0; e < 16; ++e) {
        const int c  = s * 16 + e;
        const int mg = m0 + ch * 64 + c;                  // within-batch m
        const int qx = ((q6 >> 2) ^ (c & 15)) * 4 + (q6 & 3);
        const float dot = U.Ct[c * 64 + qx];
        const float d2a = sqq + sqb[mg] - 2.0f * dot;
        if (rh == 0) {
          if (mg != qb && d2a < tv0[9]) {
            tv0[9] = d2a; ti0[9] = mg;
#pragma unroll
            for (int k2 = 9; k2 > 0; --k2)
              if (tv0[k2] < tv0[k2 - 1]) {
                float tf2 = tv0[k2]; tv0[k2] = tv0[k2 - 1]; tv0[k2 - 1] = tf2;
                int tix = ti0[k2]; ti0[k2] = ti0[k2 - 1]; ti0[k2 - 1] = tix;
              }
          }
        } else {
          if (mg != qb && d2a < tv1[9]) {
            tv1[9] = d2a; ti1[9] = mg;
#pragma unroll
            for (int k2 = 9; k2 > 0; --k2)
              if (tv1[k2] < tv1[k2 - 1]) {
                float tf2 = tv1[k2]; tv1[k2] = tv1[k2 - 1]; tv1[k2 - 1] = tf2;
                int tix = ti1[k2]; ti1[k2] = ti1[k2 - 1]; ti1[k2 - 1] = tix;
              }
          }
        }
      }
    }
  }

  // ---- merge per rh-half: 4 slices x top-10 -> threshold -> candidate list ----
  const float mn2 = __uint_as_float(maxn2u[b]);
#pragma unroll
  for (int rh = 0; rh < 2; ++rh) {
    __syncthreads();
#pragma unroll
    for (int j = 0; j < 10; ++j) {
      U.M.mv[q6][t >> 6][j] = rh ? tv1[j] : tv0[j];
      U.M.mi[q6][t >> 6][j] = (ushort_t)(rh ? ti1[j] : ti0[j]);
    }
    __syncthreads();
    if (t < 64) {
      const int q = q0 + rh * 64 + t;
      float t5[5] = {3.0e38f, 3.0e38f, 3.0e38f, 3.0e38f, 3.0e38f};
      for (int s = 0; s < 4; ++s)
#pragma unroll
        for (int j = 0; j < 10; ++j) {
          const float v = U.M.mv[t][s][j];
          if (v < t5[4]) {
            t5[4] = v;
#pragma unroll
            for (int k2 = 4; k2 > 0; --k2)
              if (t5[k2] < t5[k2 - 1]) { float tf2 = t5[k2]; t5[k2] = t5[k2 - 1]; t5[k2 - 1] = tf2; }
          }
        }
      // provably-sound margin: 2x the deterministic bf16 dot-error bound 2^-7*|q||m|
      const float T = t5[4] + 0.016f * sqrtf(sqb[q] * mn2) + 0.01f;
      int cnt = 0, ov = 0;
      int* cq = cand + ((size_t)(b * NTOK + q) * 2 + hf) * (CAND + 1);
      for (int s = 0; s < 4; ++s) {
        if (U.M.mv[t][s][9] <= T) ov = 1;                 // slice may hide candidates
#pragma unroll
        for (int j = 0; j < 10; ++j) {
          const float v = U.M.mv[t][s][j];
          if (v <= T) {
            if (cnt < CAND) cq[1 + cnt] = (int)U.M.mi[t][s][j];
            ++cnt;
          }
        }
      }
      if (cnt > CAND) { ov = 1; cnt = CAND; }
      cq[0] = cnt;
      if (ov) {                                            // cheap parallel redo later
        const unsigned int slot = atomicAdd(ovcnt, 1u);
        if (slot < OVCAP) ovlist[slot] = b * NTOK + q;
      }
    }
  }
}

// ---------------- kernel 3: exact f64 kNN distance on candidates (no fallback) --
__global__ __launch_bounds__(256) void exact_knn_kernel(
    const float* __restrict__ x, const int* __restrict__ cand,
    double* __restrict__ dk2) {
  const int qg = blockIdx.x * 4 + (threadIdx.x >> 6);     // [0, BATCH*NTOK)
  const int l  = threadIdx.x & 63;
  const int b  = qg >> 12;
  const int q  = qg & (NTOK - 1);
  const float* xb = x + (size_t)b * NTOK * DIM;
  const int* c0 = cand + ((size_t)qg * 2 + 0) * (CAND + 1);
  const int* c1 = cand + ((size_t)qg * 2 + 1) * (CAND + 1);
  const int n0 = c0[0], n1 = c1[0];

  double xq[4];
#pragma unroll
  for (int i = 0; i < 4; ++i) xq[i] = (double)xb[(size_t)q * DIM + l + i * 64];

  double t5[5] = {1e300, 1e300, 1e300, 1e300, 1e300};
  const int n_iter = n0 + n1;
  for (int c = 0; c < n_iter; ++c) {
    const int m = (c < n0) ? c0[1 + c] : c1[1 + (c - n0)];
    double acc = 0.0;
#pragma unroll
    for (int i = 0; i < 4; ++i) {
      const double d = xq[i] - (double)xb[(size_t)m * DIM + l + i * 64];
      acc += d * d;
    }
#pragma unroll
    for (int off = 32; off > 0; off >>= 1) acc += __shfl_xor(acc, off, 64);
    if (acc < t5[4]) {
      t5[4] = acc;
#pragma unroll
      for (int k2 = 4; k2 > 0; --k2)
        if (t5[k2] < t5[k2 - 1]) { double tmp = t5[k2]; t5[k2] = t5[k2 - 1]; t5[k2 - 1] = tmp; }
    }
  }
  if (l == 0) dk2[qg] = t5[4];
}

// ---- merge two sorted-ascending 5-lists, keep smallest 5 (k-th = min max) ----
#define MERGE5(a0,a1,a2,a3,a4,b0,b1,b2,b3,b4)                                   \
  {                                                                             \
    double r0 = fmin(a0, b0);                                                   \
    double r1 = fmin(fmax(a0, b0), fmin(a1, b1));                               \
    double r2 = fmin(fmin(fmax(a0, b2), fmax(a2, b0)), fmax(a1, b1));           \
    double r3 = fmin(fmin(fmax(a0, b3), fmax(a3, b0)),                          \
                     fmin(fmax(a1, b2), fmax(a2, b1)));                         \
    double r4 = fmin(fmin(fmin(fmax(a0, b4), fmax(a4, b0)),                     \
                          fmin(fmax(a1, b3), fmax(a3, b1))), fmax(a2, b2));     \
    a0 = r0; a1 = r1; a2 = r2; a3 = r3; a4 = r4;                                \
  }

// ---------------- kernel 3b: parallel full rescan for ov-flagged queries --------
__global__ __launch_bounds__(256) void fallback_kernel(
    const float* __restrict__ x, const int* __restrict__ ovlist,
    const unsigned int* __restrict__ ovcnt, double* __restrict__ dk2) {
  __shared__ float qrow[DIM];
  __shared__ double tl[256][5];
  const int t = threadIdx.x;
  unsigned int n = *ovcnt;
  if (n > OVCAP) n = OVCAP;
  for (unsigned int it = blockIdx.x; it < n; it += gridDim.x) {
    const int qg = ovlist[it];
    const int b = qg >> 12, q = qg & (NTOK - 1);
    const float* xb = x + (size_t)b * NTOK * DIM;
    __syncthreads();                                      // qrow reuse safety
    if (t < 64) ((float4*)qrow)[t] = ((const float4*)(xb + (size_t)q * DIM))[t];
    __syncthreads();
    double t5[5] = {1e300, 1e300, 1e300, 1e300, 1e300};
    for (int mm = 0; mm < NTOK / 256; ++mm) {
      const int m = mm * 256 + t;
      if (m == q) continue;
      const float4* mr = (const float4*)(xb + (size_t)m * DIM);
      double acc = 0.0;
#pragma unroll 8
      for (int d4 = 0; d4 < DIM / 4; ++d4) {
        const float4 mv = mr[d4];
        const float4 qv = ((const float4*)qrow)[d4];
        double dx = (double)qv.x - (double)mv.x; acc += dx * dx;
        dx = (double)qv.y - (double)mv.y; acc += dx * dx;
        dx = (double)qv.z - (double)mv.z; acc += dx * dx;
        dx = (double)qv.w - (double)mv.w; acc += dx * dx;
      }
      if (acc < t5[4]) {
        t5[4] = acc;
#pragma unroll
        for (int k2 = 4; k2 > 0; --k2)
          if (t5[k2] < t5[k2 - 1]) { double tmp = t5[k2]; t5[k2] = t5[k2 - 1]; t5[k2 - 1] = tmp; }
      }
    }
#pragma unroll
    for (int j = 0; j < 5; ++j) tl[t][j] = t5[j];
    __syncthreads();
    if (t < 64) {
      double m0 = tl[t][0], m1 = tl[t][1], m2 = tl[t][2], m3 = tl[t][3], m4 = tl[t][4];
#pragma unroll
      for (int s = 1; s < 4; ++s) {
        double b0 = tl[t + s * 64][0], b1 = tl[t + s * 64][1], b2 = tl[t + s * 64][2],
               b3 = tl[t + s * 64][3], b4 = tl[t + s * 64][4];
        MERGE5(m0, m1, m2, m3, m4, b0, b1, b2, b3, b4);
      }
#pragma unroll
      for (int off = 32; off > 0; off >>= 1) {
        double b0 = __shfl_down(m0, off, 64), b1 = __shfl_down(m1, off, 64),
               b2 = __shfl_down(m2, off, 64), b3 = __shfl_down(m3, off, 64),
               b4 = __shfl_down(m4, off, 64);
        MERGE5(m0, m1, m2, m3, m4, b0, b1, b2, b3, b4);
      }
      if (t == 0) dk2[qg] = m4;
    }
  }
}

// ---------------- kernel 4: gumbel + score (f64) ----------------
__global__ __launch_bounds__(256) void score_kernel(const double* __restrict__ dk2,
                                                    double* __restrict__ scores) {
  const int i = blockIdx.x * 256 + threadIdx.x;
  const uint32_t bits = threefry_bits32(0u, (uint32_t)i);
  const uint32_t fb = (bits >> 9) | 0x3F800000u;
  float uf = __uint_as_float(fb) - 1.0f;
  const float tiny = 1.17549435082228750797e-38f;
  uf += tiny;
  if (uf < tiny) uf = tiny;
  const double g = -log(-log((double)uf));
  const double w = sqrt(dk2[i] + 1e-12);
  scores[i] = log(w + 1e-12) + g;
}

// ---------------- kernel 5: stable rank-select top-256 --------------------------
__global__ __launch_bounds__(256) void rank_topk_kernel(
    const double* __restrict__ scores, int* __restrict__ sel) {
  __shared__ double K[NTOK];                              // 32 KB
  const int b   = blockIdx.x >> 4;
  const int seg = blockIdx.x & 15;
  const int t   = threadIdx.x;
  for (int i = t; i < NTOK; i += 256) K[i] = scores[(size_t)b * NTOK + i];
  __syncthreads();
  const int i = seg * 256 + t;
  const double ki = K[i];
  int r = 0;
  for (int j = 0; j < NTOK; j += 4) {
#pragma unroll
    for (int u = 0; u < 4; ++u) {
      const double kj = K[j + u];
      r += (kj > ki || (kj == ki && (j + u) < i)) ? 1 : 0;
    }
  }
  if (r < SK) sel[b * SK + r] = i;
}

// ---------------- kernel 6: gather sampled rows ----------------
__global__ __launch_bounds__(256) void gather_kernel(const float* __restrict__ x,
                                                     const int* __restrict__ sel,
                                                     float* __restrict__ out) {
  const int blk = blockIdx.x;                             // BATCH*SK blocks
  const int b = blk >> 8;
  const int r = blk & 255;
  const int t = threadIdx.x;
  const int src = sel[b * SK + r];
  out[((size_t)(b * SK + r)) * DIM + t] = x[((size_t)(b * NTOK + src)) * DIM + t];
  if (blk == 0 && t == 0) out[(size_t)BATCH * SK * DIM] = 0.0f;  // 2nd output: 0.0
}

extern "C" void kernel_launch(void* const* d_in, const int* in_sizes, int n_in,
                              void* d_out, int out_size, void* d_ws, size_t ws_size,
                              hipStream_t stream) {
  const float* x = (const float*)d_in[0];
  float* out = (float*)d_out;
  char* ws = (char*)d_ws;

  ushort_t* xh        = (ushort_t*)(ws + 0);              // 16 MB
  float*    sqf       = (float*)(ws + 16777216);          // 128 KB
  unsigned int* maxn2 = (unsigned int*)(ws + 16908288);   // 32 B
  unsigned int* ovcnt = (unsigned int*)(ws + 16908352);   // 4 B
  double*   dk2       = (double*)(ws + 16908544);         // 256 KB
  double*   scores    = (double*)(ws + 17170688);         // 256 KB
  int*      sel       = (int*)(ws + 17432832);            // 8 KB
  int*      ovlist    = (int*)(ws + 17441024);            // 256 KB
  int*      cand      = (int*)(ws + 17697280);            // ~8.7 MB (total ~26.4 MB)

  init_kernel<<<1, 64, 0, stream>>>(maxn2, ovcnt);
  split_rowsq_kernel<<<BATCH * NTOK / 4, 256, 0, stream>>>(x, xh, sqf, maxn2);
  gemm_knn_kernel<<<BATCH * 64, 256, 0, stream>>>(xh, sqf, maxn2, cand, ovcnt, ovlist);
  exact_knn_kernel<<<BATCH * NTOK / 4, 256, 0, stream>>>(x, cand, dk2);
  fallback_kernel<<<128, 256, 0, stream>>>(x, ovlist, ovcnt, dk2);
  score_kernel<<<BATCH * NTOK / 256, 256, 0, stream>>>(dk2, scores);
  rank_topk_kernel<<<BATCH * 16, 256, 0, stream>>>(scores, sel);
  gather_kernel<<<BATCH * SK, 256, 0, stream>>>(x, sel, out);
}